// Round 13
// baseline (47.827 us; speedup 1.0000x reference)
//
#include <hip/hip_runtime.h>
#include <math.h>

// Problem constants (fixed shapes from reference)
#define BATCH   8
#define HGRID   64
#define WGRID   64
#define DDIM    256
#define NPTS    1024
#define ROWS    65          // HGRID + 1 (NaN pad row 0)
#define COLS    65
#define KWIN    15          // (2*R_WIN+1)*(2*C_WIN+1) = 3*5
#define BN      (BATCH*NPTS)

#define PIDS_PER_BLK 16
#define THREADS      512    // 8 waves; Phase B: 2 pids per wave
#define NREG         9      // staged q rows in registers
#define NLDS         6      // staged q rows in LDS (per wave slab)

typedef __attribute__((ext_vector_type(8))) short bf16x8;
typedef __attribute__((ext_vector_type(4))) float f32x4;

// Direct-to-LDS 16B/lane: dest = wave-uniform base + lane*16.
__device__ __forceinline__ void gload_lds16(const float* src, float* dst) {
    __builtin_amdgcn_global_load_lds(
        (const __attribute__((address_space(1))) unsigned int*)src,
        (__attribute__((address_space(3))) unsigned int*)dst, 16, 0, 0);
}

// ---------------------------------------------------------------------------
// Fused v8 = v7 (35.5us best) with ONE rebalance: 9 reg rows + 6 LDS rows
// (was 8+7) -> smem 48KB -> 3 blocks/CU = 24 waves/CU (was 2 blocks, 16).
// __launch_bounds__(512,6) caps VGPR at 85 (live ~60, no spills).
// ---------------------------------------------------------------------------
__global__ __launch_bounds__(THREADS, 6) void fused_local_attn(
        const float* __restrict__ q,
        const float* __restrict__ c_t,
        const float* __restrict__ p_t,
        const float* __restrict__ W,
        float* __restrict__ out) {

    __shared__ __align__(16) float smem[NLDS * DDIM * 8];   // 48 KB
    float (*Pr)[DDIM] = reinterpret_cast<float (*)[DDIM]>(smem);  // 16KB alias

    const int t    = threadIdx.x;
    const int w    = t >> 6;          // wave 0..7
    const int lane = t & 63;
    const int l15  = lane & 15;
    const int g    = lane >> 4;       // k-group 0..3
    const int pid0 = blockIdx.x * PIDS_PER_BLK;
    const int dq   = w * 32;          // this wave's 32-col d-slice
    float* qsw = smem + w * (NLDS * DDIM);   // this wave's staging slab

    // ---------------- Phase A: proj into LDS (v2/v7 verbatim) -------------
    f32x4 acc0 = (f32x4)0.f;
    f32x4 acc1 = (f32x4)0.f;

    const float* ap  = &c_t[(size_t)(pid0 + l15) * DDIM + g * 8];
    const float* wp0 = &W[(size_t)(g * 8) * DDIM + dq + l15];        // df=0
    const float* wp1 = wp0 + 16;                                      // df=1

    #pragma unroll 2
    for (int kt = 0; kt < 8; ++kt) {
        const float4 a01 = *reinterpret_cast<const float4*>(ap + kt * 32);
        const float4 a23 = *reinterpret_cast<const float4*>(ap + kt * 32 + 4);
        const float af[8] = {a01.x, a01.y, a01.z, a01.w, a23.x, a23.y, a23.z, a23.w};
        union { bf16x8 v; unsigned u[4]; } AH, AL;
        #pragma unroll
        for (int i = 0; i < 4; ++i) {
            const unsigned u0 = __float_as_uint(af[2 * i]);
            const unsigned u1 = __float_as_uint(af[2 * i + 1]);
            AH.u[i] = __builtin_amdgcn_perm(u1, u0, 0x07060302u);
            const float l0 = af[2 * i]     - __uint_as_float(u0 & 0xFFFF0000u);
            const float l1 = af[2 * i + 1] - __uint_as_float(u1 & 0xFFFF0000u);
            AL.u[i] = __builtin_amdgcn_perm(__float_as_uint(l1), __float_as_uint(l0),
                                            0x07060302u);
        }

        #pragma unroll
        for (int df = 0; df < 2; ++df) {
            const float* wp = (df == 0) ? wp0 : wp1;
            float bf[8];
            #pragma unroll
            for (int i = 0; i < 8; ++i)
                bf[i] = wp[(size_t)(kt * 32 + i) * DDIM];
            union { bf16x8 v; unsigned u[4]; } BH, BL;
            #pragma unroll
            for (int i = 0; i < 4; ++i) {
                const unsigned u0 = __float_as_uint(bf[2 * i]);
                const unsigned u1 = __float_as_uint(bf[2 * i + 1]);
                BH.u[i] = __builtin_amdgcn_perm(u1, u0, 0x07060302u);
                const float l0 = bf[2 * i]     - __uint_as_float(u0 & 0xFFFF0000u);
                const float l1 = bf[2 * i + 1] - __uint_as_float(u1 & 0xFFFF0000u);
                BL.u[i] = __builtin_amdgcn_perm(__float_as_uint(l1), __float_as_uint(l0),
                                                0x07060302u);
            }
            f32x4 a = (df == 0) ? acc0 : acc1;
            a = __builtin_amdgcn_mfma_f32_16x16x32_bf16(AH.v, BH.v, a, 0, 0, 0);
            a = __builtin_amdgcn_mfma_f32_16x16x32_bf16(AH.v, BL.v, a, 0, 0, 0);
            a = __builtin_amdgcn_mfma_f32_16x16x32_bf16(AL.v, BH.v, a, 0, 0, 0);
            if (df == 0) acc0 = a; else acc1 = a;
        }
    }

    // C/D layout: col = lane&15, row = (lane>>4)*4 + reg  [m89-verified]
    #pragma unroll
    for (int r = 0; r < 4; ++r) {
        Pr[g * 4 + r][dq +  0 + l15] = acc0[r];
        Pr[g * 4 + r][dq + 16 + l15] = acc1[r];
    }
    __syncthreads();

    // Snapshot both pr rows, then Pr's LDS is recycled as staging space.
    const float4 prA = *reinterpret_cast<const float4*>(&Pr[w * 2 + 0][lane * 4]);
    const float4 prB = *reinterpret_cast<const float4*>(&Pr[w * 2 + 1][lane * 4]);
    __syncthreads();

    // ---------------- Phase B: attention, 2 pids per wave -----------------
    #pragma unroll 1
    for (int pp = 0; pp < 2; ++pp) {
        const int pl  = w * 2 + pp;            // pid-local 0..15
        const int pid = pid0 + pl;
        const int b   = pid >> 10;             // / NPTS
        const float4 pr = pp ? prB : prA;
        const float2 ppos = *reinterpret_cast<const float2*>(&p_t[pid * 2]);
        const float p0f = ppos.x;
        const float p1f = ppos.y;
        const int p0 = (int)p0f;
        const int p1 = (int)p1f;

        float re[3], ce[5];
        int rowidx[3], colidx[5];
        #pragma unroll
        for (int i = 0; i < 3; ++i) {
            int rr = p0 + i;
            rr = rr > ROWS ? ROWS : rr;
            rr = (rr == ROWS) ? 0 : rr;        // % ROWS
            rowidx[i] = rr;
            const float rf = (float)(rr - 1 > 0 ? rr - 1 : 0);
            const float dr = rf - p0f;         // / R_WIN (=1)
            re[i] = __expf(-2.0f * dr * dr);
        }
        #pragma unroll
        for (int j = 0; j < 5; ++j) {
            int cc = p1 + j - 1;
            cc = cc < 0 ? 0 : (cc > COLS ? COLS : cc);
            cc = (cc == COLS) ? 0 : cc;        // % COLS
            colidx[j] = cc;
            const float cf = (float)(cc - 1 > 0 ? cc - 1 : 0);
            const float dc = (cf - p1f) * 0.5f; // / C_WIN (=2)
            ce[j] = __expf(-2.0f * dc * dc);
        }

        // Fence: previous round's LDS reads must retire before async writes
        // to the same slab can be issued (vmcnt and lgkmcnt are separate).
        asm volatile("s_waitcnt lgkmcnt(0)" ::: "memory");
        __builtin_amdgcn_sched_barrier(0);

        // ---- Issue ALL 15 gathers: rows 0..NREG-1 -> regs, rest -> LDS ----
        float4 qg[NREG];
        unsigned vmask = 0;
        #pragma unroll
        for (int k = 0; k < KWIN; ++k) {
            const int i = k / 5, j = k % 5;
            const int rr = rowidx[i];
            const int cc = colidx[j];
            const bool valid = (rr != 0) && (cc != 0);   // wave-uniform
            const float* src =
                &q[((size_t)((b * HGRID + rr - 1) * WGRID + cc - 1)) * DDIM + lane * 4];
            if (k < NREG) {
                float4 v = make_float4(0.f, 0.f, 0.f, 0.f);
                if (valid) v = *reinterpret_cast<const float4*>(src);
                qg[k] = v;
            } else {
                if (valid) gload_lds16(src, &qsw[(k - NREG) * DDIM]);
            }
            if (valid) vmask |= (1u << k);
        }
        asm volatile("s_waitcnt vmcnt(0)" ::: "memory");   // ONE wait for all 15
        // Pin register rows once (post-drain: no serialization, no remat).
        #pragma unroll
        for (int k = 0; k < NREG; ++k)
            asm volatile("" : "+v"(qg[k].x), "+v"(qg[k].y), "+v"(qg[k].z), "+v"(qg[k].w));

        // ---- Scores ----
        float score[KWIN];
        #pragma unroll
        for (int k = 0; k < NREG; ++k) {
            const float4 v = qg[k];
            score[k] = fmaf(v.x, pr.x, fmaf(v.y, pr.y, fmaf(v.z, pr.z, v.w * pr.w)));
        }
        #pragma unroll
        for (int k = NREG; k < KWIN; ++k) {
            const float4 v =
                *reinterpret_cast<const float4*>(&qsw[(k - NREG) * DDIM + lane * 4]);
            score[k] = fmaf(v.x, pr.x, fmaf(v.y, pr.y, fmaf(v.z, pr.z, v.w * pr.w)));
        }

        // ---- 15 independent butterfly reductions ----
        #pragma unroll
        for (int k = 0; k < KWIN; ++k) {
            float s = score[k];
            #pragma unroll
            for (int off = 32; off; off >>= 1) s += __shfl_xor(s, off, 64);
            score[k] = ((vmask >> k) & 1u) ? s : -INFINITY;
        }

        // ---- Softmax over K=15 (replicated across lanes) ----
        float mx = score[0];
        #pragma unroll
        for (int k = 1; k < KWIN; ++k) mx = fmaxf(mx, score[k]);
        float sum = 0.f;
        #pragma unroll
        for (int k = 0; k < KWIN; ++k) {
            const float e = __expf(score[k] - mx);
            score[k] = e;
            sum += e;
        }
        const float inv = 1.0f / sum;

        // ---- Weighted sum: reg rows + LDS rows ----
        float ox = 0.f, oy = 0.f, oz = 0.f, ow = 0.f;
        #pragma unroll
        for (int k = 0; k < KWIN; ++k) {
            const int i = k / 5, j = k % 5;
            const float wk = score[k] * inv * re[i] * ce[j];
            if (k < NREG) {
                ox = fmaf(wk, qg[k].x, ox);
                oy = fmaf(wk, qg[k].y, oy);
                oz = fmaf(wk, qg[k].z, oz);
                ow = fmaf(wk, qg[k].w, ow);
            } else if ((vmask >> k) & 1u) {   // guard: stale LDS may be NaN
                const float4 v =
                    *reinterpret_cast<const float4*>(&qsw[(k - NREG) * DDIM + lane * 4]);
                ox = fmaf(wk, v.x, ox);
                oy = fmaf(wk, v.y, oy);
                oz = fmaf(wk, v.z, oz);
                ow = fmaf(wk, v.w, ow);
            }
        }
        *reinterpret_cast<float4*>(&out[(size_t)pid * DDIM + lane * 4]) =
            make_float4(ox, oy, oz, ow);
    }
}

// ---------------------------------------------------------------------------
extern "C" void kernel_launch(void* const* d_in, const int* in_sizes, int n_in,
                              void* d_out, int out_size, void* d_ws, size_t ws_size,
                              hipStream_t stream) {
    const float* q   = (const float*)d_in[0];
    const float* c_t = (const float*)d_in[1];
    const float* p_t = (const float*)d_in[2];
    const float* W_a = (const float*)d_in[3];
    float* out = (float*)d_out;

    fused_local_attn<<<BN / PIDS_PER_BLK, THREADS, 0, stream>>>(q, c_t, p_t, W_a, out);
}

// Round 14
// 42.207 us; speedup vs baseline: 1.1331x; 1.1331x over previous
//
#include <hip/hip_runtime.h>
#include <math.h>

// Problem constants (fixed shapes from reference)
#define BATCH   8
#define HGRID   64
#define WGRID   64
#define DDIM    256
#define NPTS    1024
#define ROWS    65          // HGRID + 1 (NaN pad row 0)
#define COLS    65
#define KWIN    15          // (2*R_WIN+1)*(2*C_WIN+1) = 3*5
#define BN      (BATCH*NPTS)

#define NREG    10          // attn: staged q rows in registers
#define NLDS    5           // attn: staged q rows in LDS per wave

typedef __attribute__((ext_vector_type(8))) short bf16x8;
typedef __attribute__((ext_vector_type(4))) float f32x4;

// Direct-to-LDS 16B/lane: dest = wave-uniform base + lane*16.
__device__ __forceinline__ void gload_lds16(const float* src, float* dst) {
    __builtin_amdgcn_global_load_lds(
        (const __attribute__((address_space(1))) unsigned int*)src,
        (__attribute__((address_space(3))) unsigned int*)dst, 16, 0, 0);
}

// ---------------------------------------------------------------------------
// Kernel 1: W_a[c][d] -> WHT[d][c], WLT[d][c] (bf16 hi + residual).
// 32x32 LDS tile transpose. Grid (8,8). (R10-proven)
// ---------------------------------------------------------------------------
__global__ __launch_bounds__(256) void prep_w(const float* __restrict__ W,
                                              ushort* __restrict__ WHT,
                                              ushort* __restrict__ WLT) {
    __shared__ float Ls[32][33];
    const int t  = threadIdx.x;
    const int tx = t & 31;
    const int ty = t >> 5;              // 0..7
    const int d0 = blockIdx.x * 32;
    const int c0 = blockIdx.y * 32;
    #pragma unroll
    for (int r = 0; r < 4; ++r) {
        const int row = ty + r * 8;
        Ls[row][tx] = W[(c0 + row) * DDIM + d0 + tx];
    }
    __syncthreads();
    #pragma unroll
    for (int r = 0; r < 4; ++r) {
        const int row = ty + r * 8;     // d-local
        const float f = Ls[tx][row];    // = W[c0+tx][d0+row]
        const unsigned u = __float_as_uint(f);
        const float res = f - __uint_as_float(u & 0xFFFF0000u);
        WHT[(d0 + row) * DDIM + c0 + tx] = (ushort)(u >> 16);
        WLT[(d0 + row) * DDIM + c0 + tx] = (ushort)(__float_as_uint(res) >> 16);
    }
}

// ---------------------------------------------------------------------------
// Kernel 2: proj = c_t x W_a, 3-term split-bf16 MFMA. Block 256 (4 waves),
// BM=64, BN=64, grid (128,4). W staged in LDS once per block. (R10-proven)
// ---------------------------------------------------------------------------
__global__ __launch_bounds__(256) void proj_gemm(const float* __restrict__ C,
                                                 const ushort* __restrict__ WHT,
                                                 const ushort* __restrict__ WLT,
                                                 float* __restrict__ P) {
    __shared__ __align__(16) ushort BHs[64][40];   // [col][k] pitch 80B
    __shared__ __align__(16) ushort BLs[64][40];

    const int t    = threadIdx.x;
    const int wv   = t >> 6;
    const int lane = t & 63;
    const int l15  = lane & 15;
    const int g    = lane >> 4;            // k-subgroup 0..3
    const int m0   = blockIdx.x * 64;
    const int n0   = blockIdx.y * 64;
    const int scol  = t >> 2;              // staging: col 0..63
    const int spart = t & 3;               // staging: k-part (8 ushorts)

    f32x4 acc[4];
    #pragma unroll
    for (int df = 0; df < 4; ++df) acc[df] = (f32x4)0.0f;

    const int arow = m0 + wv * 16 + l15;

    for (int kt = 0; kt < 8; ++kt) {
        __syncthreads();
        *reinterpret_cast<uint4*>(&BHs[scol][spart * 8]) =
            *reinterpret_cast<const uint4*>(&WHT[(n0 + scol) * DDIM + kt * 32 + spart * 8]);
        *reinterpret_cast<uint4*>(&BLs[scol][spart * 8]) =
            *reinterpret_cast<const uint4*>(&WLT[(n0 + scol) * DDIM + kt * 32 + spart * 8]);
        __syncthreads();

        const float* ap = &C[(size_t)arow * DDIM + kt * 32 + g * 8];
        const float4 a01 = *reinterpret_cast<const float4*>(ap);
        const float4 a23 = *reinterpret_cast<const float4*>(ap + 4);
        const float af[8] = {a01.x, a01.y, a01.z, a01.w, a23.x, a23.y, a23.z, a23.w};
        union { bf16x8 v; unsigned u[4]; } AH, AL;
        #pragma unroll
        for (int i = 0; i < 4; ++i) {
            const unsigned u0 = __float_as_uint(af[2 * i]);
            const unsigned u1 = __float_as_uint(af[2 * i + 1]);
            AH.u[i] = __builtin_amdgcn_perm(u1, u0, 0x07060302u);
            const float l0 = af[2 * i]     - __uint_as_float(u0 & 0xFFFF0000u);
            const float l1 = af[2 * i + 1] - __uint_as_float(u1 & 0xFFFF0000u);
            AL.u[i] = __builtin_amdgcn_perm(__float_as_uint(l1), __float_as_uint(l0),
                                            0x07060302u);
        }

        #pragma unroll
        for (int df = 0; df < 4; ++df) {
            union { uint4 u; bf16x8 v; } BH, BL;
            BH.u = *reinterpret_cast<const uint4*>(&BHs[df * 16 + l15][g * 8]);
            BL.u = *reinterpret_cast<const uint4*>(&BLs[df * 16 + l15][g * 8]);
            acc[df] = __builtin_amdgcn_mfma_f32_16x16x32_bf16(AH.v, BH.v, acc[df], 0, 0, 0);
            acc[df] = __builtin_amdgcn_mfma_f32_16x16x32_bf16(AH.v, BL.v, acc[df], 0, 0, 0);
            acc[df] = __builtin_amdgcn_mfma_f32_16x16x32_bf16(AL.v, BH.v, acc[df], 0, 0, 0);
        }
    }

    // C/D layout: col = lane&15, row = (lane>>4)*4 + reg  [m89-verified]
    #pragma unroll
    for (int df = 0; df < 4; ++df)
        #pragma unroll
        for (int r = 0; r < 4; ++r)
            P[(size_t)(m0 + wv * 16 + g * 4 + r) * DDIM + n0 + df * 16 + l15] = acc[df][r];
}

// ---------------------------------------------------------------------------
// Kernel 3 (attn v9): 1 pid per wave, 8 pids / 512-thr block, grid 1024
// (4 blocks/CU). v7-proven hybrid gather engine: rows 0..9 -> registers,
// rows 10..14 -> global_load_lds; all 15 + pr in flight, ONE vmcnt(0),
// pin after drain. 40KB LDS. No barriers (waves independent).
// XCD swizzle: batch b's 128 blocks land on one XCD (q[b]=4MB fits its L2).
// ---------------------------------------------------------------------------
__global__ __launch_bounds__(512, 4) void local_attn(const float* __restrict__ q,
                                                     const float* __restrict__ p_t,
                                                     const float* __restrict__ proj,
                                                     float* __restrict__ out) {
    __shared__ __align__(16) float qs[8][NLDS * DDIM];   // 40 KB

    const int w    = threadIdx.x >> 6;
    const int lane = threadIdx.x & 63;
    // XCD swizzle (1024 blocks, 8 XCDs, round-robin bid%8): work index
    // wk = (bid&7)*128 + bid>>3 puts each batch's blocks on one XCD.
    const int bid  = blockIdx.x;
    const int wk   = (bid & 7) * 128 + (bid >> 3);
    const int pid  = wk * 8 + w;
    const int b    = pid >> 10;
    float* qsw = &qs[w][0];

    const float2 pp = *reinterpret_cast<const float2*>(&p_t[pid * 2]);
    const float p0f = pp.x;
    const float p1f = pp.y;
    const int p0 = (int)p0f;
    const int p1 = (int)p1f;

    // pr joins the in-flight batch (issued before the drain)
    const float4 pr = *reinterpret_cast<const float4*>(&proj[(size_t)pid * DDIM + lane * 4]);

    float re[3], ce[5];
    int rowidx[3], colidx[5];
    #pragma unroll
    for (int i = 0; i < 3; ++i) {
        int rr = p0 + i;
        rr = rr > ROWS ? ROWS : rr;
        rr = (rr == ROWS) ? 0 : rr;        // % ROWS
        rowidx[i] = rr;
        const float rf = (float)(rr - 1 > 0 ? rr - 1 : 0);
        const float dr = rf - p0f;         // / R_WIN (=1)
        re[i] = __expf(-2.0f * dr * dr);
    }
    #pragma unroll
    for (int j = 0; j < 5; ++j) {
        int cc = p1 + j - 1;
        cc = cc < 0 ? 0 : (cc > COLS ? COLS : cc);
        cc = (cc == COLS) ? 0 : cc;        // % COLS
        colidx[j] = cc;
        const float cf = (float)(cc - 1 > 0 ? cc - 1 : 0);
        const float dc = (cf - p1f) * 0.5f; // / C_WIN (=2)
        ce[j] = __expf(-2.0f * dc * dc);
    }

    // ---- Issue ALL 15 gathers: rows 0..NREG-1 -> regs, rest -> LDS ----
    float4 qg[NREG];
    unsigned vmask = 0;
    #pragma unroll
    for (int k = 0; k < KWIN; ++k) {
        const int i = k / 5, j = k % 5;
        const int rr = rowidx[i];
        const int cc = colidx[j];
        const bool valid = (rr != 0) && (cc != 0);   // wave-uniform
        const float* src =
            &q[((size_t)((b * HGRID + rr - 1) * WGRID + cc - 1)) * DDIM + lane * 4];
        if (k < NREG) {
            float4 v = make_float4(0.f, 0.f, 0.f, 0.f);
            if (valid) v = *reinterpret_cast<const float4*>(src);
            qg[k] = v;
        } else {
            if (valid) gload_lds16(src, &qsw[(k - NREG) * DDIM]);
        }
        if (valid) vmask |= (1u << k);
    }
    asm volatile("s_waitcnt vmcnt(0)" ::: "memory");   // ONE wait for all
    #pragma unroll
    for (int k = 0; k < NREG; ++k)
        asm volatile("" : "+v"(qg[k].x), "+v"(qg[k].y), "+v"(qg[k].z), "+v"(qg[k].w));

    // ---- Scores ----
    float score[KWIN];
    #pragma unroll
    for (int k = 0; k < NREG; ++k) {
        const float4 v = qg[k];
        score[k] = fmaf(v.x, pr.x, fmaf(v.y, pr.y, fmaf(v.z, pr.z, v.w * pr.w)));
    }
    #pragma unroll
    for (int k = NREG; k < KWIN; ++k) {
        const float4 v = *reinterpret_cast<const float4*>(&qsw[(k - NREG) * DDIM + lane * 4]);
        score[k] = fmaf(v.x, pr.x, fmaf(v.y, pr.y, fmaf(v.z, pr.z, v.w * pr.w)));
    }

    // ---- 15 independent butterfly reductions ----
    #pragma unroll
    for (int k = 0; k < KWIN; ++k) {
        float s = score[k];
        #pragma unroll
        for (int off = 32; off; off >>= 1) s += __shfl_xor(s, off, 64);
        score[k] = ((vmask >> k) & 1u) ? s : -INFINITY;
    }

    // ---- Softmax over K=15 (replicated across lanes) ----
    float mx = score[0];
    #pragma unroll
    for (int k = 1; k < KWIN; ++k) mx = fmaxf(mx, score[k]);
    float sum = 0.f;
    #pragma unroll
    for (int k = 0; k < KWIN; ++k) {
        const float e = __expf(score[k] - mx);
        score[k] = e;
        sum += e;
    }
    const float inv = 1.0f / sum;

    // ---- Weighted sum: reg rows + LDS rows ----
    float ox = 0.f, oy = 0.f, oz = 0.f, ow = 0.f;
    #pragma unroll
    for (int k = 0; k < KWIN; ++k) {
        const int i = k / 5, j = k % 5;
        const float wk2 = score[k] * inv * re[i] * ce[j];
        if (k < NREG) {
            ox = fmaf(wk2, qg[k].x, ox);
            oy = fmaf(wk2, qg[k].y, oy);
            oz = fmaf(wk2, qg[k].z, oz);
            ow = fmaf(wk2, qg[k].w, ow);
        } else if ((vmask >> k) & 1u) {   // guard: stale LDS may be NaN
            const float4 v =
                *reinterpret_cast<const float4*>(&qsw[(k - NREG) * DDIM + lane * 4]);
            ox = fmaf(wk2, v.x, ox);
            oy = fmaf(wk2, v.y, oy);
            oz = fmaf(wk2, v.z, oz);
            ow = fmaf(wk2, v.w, ow);
        }
    }
    *reinterpret_cast<float4*>(&out[(size_t)pid * DDIM + lane * 4]) =
        make_float4(ox, oy, oz, ow);
}

// ---------------------------------------------------------------------------
extern "C" void kernel_launch(void* const* d_in, const int* in_sizes, int n_in,
                              void* d_out, int out_size, void* d_ws, size_t ws_size,
                              hipStream_t stream) {
    const float* q   = (const float*)d_in[0];
    const float* c_t = (const float*)d_in[1];
    const float* p_t = (const float*)d_in[2];
    const float* W_a = (const float*)d_in[3];
    float* out = (float*)d_out;

    char* ws = (char*)d_ws;
    float*  proj = (float*)ws;                              // 8 MB
    ushort* WHT  = (ushort*)(ws + (8 << 20));               // 128 KB
    ushort* WLT  = (ushort*)(ws + (8 << 20) + DDIM * DDIM * 2);

    dim3 wgrid(8, 8);
    prep_w<<<wgrid, 256, 0, stream>>>(W_a, WHT, WLT);

    dim3 ggrid(BN / 64, DDIM / 64);                         // 128 x 4
    proj_gemm<<<ggrid, 256, 0, stream>>>(c_t, WHT, WLT, proj);

    local_attn<<<BN / 8, 512, 0, stream>>>(q, p_t, proj, out);
}

// Round 15
// 33.674 us; speedup vs baseline: 1.4203x; 1.2534x over previous
//
#include <hip/hip_runtime.h>
#include <math.h>

// Problem constants (fixed shapes from reference)
#define BATCH   8
#define HGRID   64
#define WGRID   64
#define DDIM    256
#define NPTS    1024
#define ROWS    65          // HGRID + 1 (NaN pad row 0)
#define COLS    65
#define KWIN    15          // (2*R_WIN+1)*(2*C_WIN+1) = 3*5
#define BN      (BATCH*NPTS)

#define PIDS_PER_BLK 16
#define THREADS      512    // 8 waves; Phase B: 2 pids per wave
#define NREG         9      // staged q rows in registers
#define NLDS         6      // staged q rows in LDS (per wave slab)

typedef __attribute__((ext_vector_type(8))) short bf16x8;
typedef __attribute__((ext_vector_type(4))) float f32x4;

// Direct-to-LDS 16B/lane: dest = wave-uniform base + lane*16.
__device__ __forceinline__ void gload_lds16(const float* src, float* dst) {
    __builtin_amdgcn_global_load_lds(
        (const __attribute__((address_space(1))) unsigned int*)src,
        (__attribute__((address_space(3))) unsigned int*)dst, 16, 0, 0);
}

// ---------------------------------------------------------------------------
// Fused v10 = v7 (35.5us best) + two changes:
//  (1) 9 reg rows + 6 LDS rows (48KB smem -> 3 blocks/CU, 24 waves/CU) at
//      the PROVEN (512,4) bound — v8's rebalance without v8's spill-cap.
//  (2) XCD swizzle: wk=(bid&7)*64+(bid>>3) -> XCD x serves exactly batch x;
//      its q slab (4MB) fits the 4MB per-XCD L2 -> gathers become L2 hits.
// Everything else byte-identical to v7.
// ---------------------------------------------------------------------------
__global__ __launch_bounds__(THREADS, 4) void fused_local_attn(
        const float* __restrict__ q,
        const float* __restrict__ c_t,
        const float* __restrict__ p_t,
        const float* __restrict__ W,
        float* __restrict__ out) {

    __shared__ __align__(16) float smem[NLDS * DDIM * 8];   // 48 KB
    float (*Pr)[DDIM] = reinterpret_cast<float (*)[DDIM]>(smem);  // 16KB alias

    const int t    = threadIdx.x;
    const int w    = t >> 6;          // wave 0..7
    const int lane = t & 63;
    const int l15  = lane & 15;
    const int g    = lane >> 4;       // k-group 0..3
    const int bid  = blockIdx.x;
    const int wk   = (bid & 7) * 64 + (bid >> 3);   // XCD-aligned work index
    const int pid0 = wk * PIDS_PER_BLK;
    const int dq   = w * 32;          // this wave's 32-col d-slice
    float* qsw = smem + w * (NLDS * DDIM);   // this wave's staging slab

    // ---------------- Phase A: proj into LDS (v7 verbatim) ----------------
    f32x4 acc0 = (f32x4)0.f;
    f32x4 acc1 = (f32x4)0.f;

    const float* ap  = &c_t[(size_t)(pid0 + l15) * DDIM + g * 8];
    const float* wp0 = &W[(size_t)(g * 8) * DDIM + dq + l15];        // df=0
    const float* wp1 = wp0 + 16;                                      // df=1

    #pragma unroll 2
    for (int kt = 0; kt < 8; ++kt) {
        const float4 a01 = *reinterpret_cast<const float4*>(ap + kt * 32);
        const float4 a23 = *reinterpret_cast<const float4*>(ap + kt * 32 + 4);
        const float af[8] = {a01.x, a01.y, a01.z, a01.w, a23.x, a23.y, a23.z, a23.w};
        union { bf16x8 v; unsigned u[4]; } AH, AL;
        #pragma unroll
        for (int i = 0; i < 4; ++i) {
            const unsigned u0 = __float_as_uint(af[2 * i]);
            const unsigned u1 = __float_as_uint(af[2 * i + 1]);
            AH.u[i] = __builtin_amdgcn_perm(u1, u0, 0x07060302u);
            const float l0 = af[2 * i]     - __uint_as_float(u0 & 0xFFFF0000u);
            const float l1 = af[2 * i + 1] - __uint_as_float(u1 & 0xFFFF0000u);
            AL.u[i] = __builtin_amdgcn_perm(__float_as_uint(l1), __float_as_uint(l0),
                                            0x07060302u);
        }

        #pragma unroll
        for (int df = 0; df < 2; ++df) {
            const float* wp = (df == 0) ? wp0 : wp1;
            float bf[8];
            #pragma unroll
            for (int i = 0; i < 8; ++i)
                bf[i] = wp[(size_t)(kt * 32 + i) * DDIM];
            union { bf16x8 v; unsigned u[4]; } BH, BL;
            #pragma unroll
            for (int i = 0; i < 4; ++i) {
                const unsigned u0 = __float_as_uint(bf[2 * i]);
                const unsigned u1 = __float_as_uint(bf[2 * i + 1]);
                BH.u[i] = __builtin_amdgcn_perm(u1, u0, 0x07060302u);
                const float l0 = bf[2 * i]     - __uint_as_float(u0 & 0xFFFF0000u);
                const float l1 = bf[2 * i + 1] - __uint_as_float(u1 & 0xFFFF0000u);
                BL.u[i] = __builtin_amdgcn_perm(__float_as_uint(l1), __float_as_uint(l0),
                                                0x07060302u);
            }
            f32x4 a = (df == 0) ? acc0 : acc1;
            a = __builtin_amdgcn_mfma_f32_16x16x32_bf16(AH.v, BH.v, a, 0, 0, 0);
            a = __builtin_amdgcn_mfma_f32_16x16x32_bf16(AH.v, BL.v, a, 0, 0, 0);
            a = __builtin_amdgcn_mfma_f32_16x16x32_bf16(AL.v, BH.v, a, 0, 0, 0);
            if (df == 0) acc0 = a; else acc1 = a;
        }
    }

    // C/D layout: col = lane&15, row = (lane>>4)*4 + reg  [m89-verified]
    #pragma unroll
    for (int r = 0; r < 4; ++r) {
        Pr[g * 4 + r][dq +  0 + l15] = acc0[r];
        Pr[g * 4 + r][dq + 16 + l15] = acc1[r];
    }
    __syncthreads();

    // Snapshot both pr rows, then Pr's LDS is recycled as staging space.
    const float4 prA = *reinterpret_cast<const float4*>(&Pr[w * 2 + 0][lane * 4]);
    const float4 prB = *reinterpret_cast<const float4*>(&Pr[w * 2 + 1][lane * 4]);
    __syncthreads();

    // ---------------- Phase B: attention, 2 pids per wave -----------------
    #pragma unroll 1
    for (int pp = 0; pp < 2; ++pp) {
        const int pl  = w * 2 + pp;            // pid-local 0..15
        const int pid = pid0 + pl;
        const int b   = pid >> 10;             // / NPTS
        const float4 pr = pp ? prB : prA;
        const float2 ppos = *reinterpret_cast<const float2*>(&p_t[pid * 2]);
        const float p0f = ppos.x;
        const float p1f = ppos.y;
        const int p0 = (int)p0f;
        const int p1 = (int)p1f;

        float re[3], ce[5];
        int rowidx[3], colidx[5];
        #pragma unroll
        for (int i = 0; i < 3; ++i) {
            int rr = p0 + i;
            rr = rr > ROWS ? ROWS : rr;
            rr = (rr == ROWS) ? 0 : rr;        // % ROWS
            rowidx[i] = rr;
            const float rf = (float)(rr - 1 > 0 ? rr - 1 : 0);
            const float dr = rf - p0f;         // / R_WIN (=1)
            re[i] = __expf(-2.0f * dr * dr);
        }
        #pragma unroll
        for (int j = 0; j < 5; ++j) {
            int cc = p1 + j - 1;
            cc = cc < 0 ? 0 : (cc > COLS ? COLS : cc);
            cc = (cc == COLS) ? 0 : cc;        // % COLS
            colidx[j] = cc;
            const float cf = (float)(cc - 1 > 0 ? cc - 1 : 0);
            const float dc = (cf - p1f) * 0.5f; // / C_WIN (=2)
            ce[j] = __expf(-2.0f * dc * dc);
        }

        // Fence: previous round's LDS reads must retire before async writes
        // to the same slab can be issued (vmcnt and lgkmcnt are separate).
        asm volatile("s_waitcnt lgkmcnt(0)" ::: "memory");
        __builtin_amdgcn_sched_barrier(0);

        // ---- Issue ALL 15 gathers: rows 0..NREG-1 -> regs, rest -> LDS ----
        float4 qg[NREG];
        unsigned vmask = 0;
        #pragma unroll
        for (int k = 0; k < KWIN; ++k) {
            const int i = k / 5, j = k % 5;
            const int rr = rowidx[i];
            const int cc = colidx[j];
            const bool valid = (rr != 0) && (cc != 0);   // wave-uniform
            const float* src =
                &q[((size_t)((b * HGRID + rr - 1) * WGRID + cc - 1)) * DDIM + lane * 4];
            if (k < NREG) {
                float4 v = make_float4(0.f, 0.f, 0.f, 0.f);
                if (valid) v = *reinterpret_cast<const float4*>(src);
                qg[k] = v;
            } else {
                if (valid) gload_lds16(src, &qsw[(k - NREG) * DDIM]);
            }
            if (valid) vmask |= (1u << k);
        }
        asm volatile("s_waitcnt vmcnt(0)" ::: "memory");   // ONE wait for all 15
        // Pin register rows once (post-drain: no serialization, no remat).
        #pragma unroll
        for (int k = 0; k < NREG; ++k)
            asm volatile("" : "+v"(qg[k].x), "+v"(qg[k].y), "+v"(qg[k].z), "+v"(qg[k].w));

        // ---- Scores ----
        float score[KWIN];
        #pragma unroll
        for (int k = 0; k < NREG; ++k) {
            const float4 v = qg[k];
            score[k] = fmaf(v.x, pr.x, fmaf(v.y, pr.y, fmaf(v.z, pr.z, v.w * pr.w)));
        }
        #pragma unroll
        for (int k = NREG; k < KWIN; ++k) {
            const float4 v =
                *reinterpret_cast<const float4*>(&qsw[(k - NREG) * DDIM + lane * 4]);
            score[k] = fmaf(v.x, pr.x, fmaf(v.y, pr.y, fmaf(v.z, pr.z, v.w * pr.w)));
        }

        // ---- 15 independent butterfly reductions ----
        #pragma unroll
        for (int k = 0; k < KWIN; ++k) {
            float s = score[k];
            #pragma unroll
            for (int off = 32; off; off >>= 1) s += __shfl_xor(s, off, 64);
            score[k] = ((vmask >> k) & 1u) ? s : -INFINITY;
        }

        // ---- Softmax over K=15 (replicated across lanes) ----
        float mx = score[0];
        #pragma unroll
        for (int k = 1; k < KWIN; ++k) mx = fmaxf(mx, score[k]);
        float sum = 0.f;
        #pragma unroll
        for (int k = 0; k < KWIN; ++k) {
            const float e = __expf(score[k] - mx);
            score[k] = e;
            sum += e;
        }
        const float inv = 1.0f / sum;

        // ---- Weighted sum: reg rows + LDS rows ----
        float ox = 0.f, oy = 0.f, oz = 0.f, ow = 0.f;
        #pragma unroll
        for (int k = 0; k < KWIN; ++k) {
            const int i = k / 5, j = k % 5;
            const float wk2 = score[k] * inv * re[i] * ce[j];
            if (k < NREG) {
                ox = fmaf(wk2, qg[k].x, ox);
                oy = fmaf(wk2, qg[k].y, oy);
                oz = fmaf(wk2, qg[k].z, oz);
                ow = fmaf(wk2, qg[k].w, ow);
            } else if ((vmask >> k) & 1u) {   // guard: stale LDS may be NaN
                const float4 v =
                    *reinterpret_cast<const float4*>(&qsw[(k - NREG) * DDIM + lane * 4]);
                ox = fmaf(wk2, v.x, ox);
                oy = fmaf(wk2, v.y, oy);
                oz = fmaf(wk2, v.z, oz);
                ow = fmaf(wk2, v.w, ow);
            }
        }
        *reinterpret_cast<float4*>(&out[(size_t)pid * DDIM + lane * 4]) =
            make_float4(ox, oy, oz, ow);
    }
}

// ---------------------------------------------------------------------------
extern "C" void kernel_launch(void* const* d_in, const int* in_sizes, int n_in,
                              void* d_out, int out_size, void* d_ws, size_t ws_size,
                              hipStream_t stream) {
    const float* q   = (const float*)d_in[0];
    const float* c_t = (const float*)d_in[1];
    const float* p_t = (const float*)d_in[2];
    const float* W_a = (const float*)d_in[3];
    float* out = (float*)d_out;

    fused_local_attn<<<BN / PIDS_PER_BLK, THREADS, 0, stream>>>(q, c_t, p_t, W_a, out);
}